// Round 1
// baseline (2048.303 us; speedup 1.0000x reference)
//
#include <hip/hip_runtime.h>

#define M_NODES 20000
#define K_FEATS 3703
#define NH 50
#define NC 6
#define N_EDGES_C 640000
#define KSPLIT 926   // ceil(3703/4)

// ---------------- GEMM1: part[s] = A[:, ks:ke] @ W1[ks:ke, :] ----------------
// grid (157, 4), block 320. BM=128, BK=32, per-thread 4 rows (stride 32) x 5 cols (stride 10).
__global__ __launch_bounds__(320) void k_gemm1(const float* __restrict__ A,
                                               const float* __restrict__ W1,
                                               float* __restrict__ part) {
  __shared__ float lA[128 * 36];
  __shared__ float lB[50 * 36];
  const int tid = threadIdx.x;
  const int row0 = blockIdx.x * 128;
  const int s = blockIdx.y;
  const int ks = s * KSPLIT;
  const int ke = (ks + KSPLIT < K_FEATS) ? ks + KSPLIT : K_FEATS;
  const int ty = tid / 10;           // 0..31
  const int tx = tid % 10;           // 0..9
  float acc[4][5] = {};

  for (int k0 = ks; k0 < ke; k0 += 32) {
    // stage A tile: 128 rows x 32 k, coalesced (lanes walk k within row)
    #pragma unroll
    for (int i = 0; i < 13; ++i) {
      int idx = tid + i * 320;
      if (idx < 4096) {
        int r = idx >> 5, kk = idx & 31;
        int gr = row0 + r, gk = k0 + kk;
        float v = (gr < M_NODES && gk < ke) ? A[gr * K_FEATS + gk] : 0.f;
        lA[r * 36 + kk] = v;
      }
    }
    // stage B transposed: lB[n][kk]
    #pragma unroll
    for (int i = 0; i < 5; ++i) {
      int idx = tid + i * 320;       // exactly covers 1600
      int kk = idx / 50, n = idx % 50;
      int gk = k0 + kk;
      float v = (gk < ke) ? W1[gk * NH + n] : 0.f;
      lB[n * 36 + kk] = v;
    }
    __syncthreads();
    #pragma unroll
    for (int kk = 0; kk < 32; kk += 4) {
      float4 av[4], bv[5];
      #pragma unroll
      for (int i = 0; i < 4; ++i)
        av[i] = *(const float4*)&lA[(ty + 32 * i) * 36 + kk];
      #pragma unroll
      for (int j = 0; j < 5; ++j)
        bv[j] = *(const float4*)&lB[(tx + 10 * j) * 36 + kk];
      #pragma unroll
      for (int i = 0; i < 4; ++i)
        #pragma unroll
        for (int j = 0; j < 5; ++j) {
          acc[i][j] = fmaf(av[i].x, bv[j].x, acc[i][j]);
          acc[i][j] = fmaf(av[i].y, bv[j].y, acc[i][j]);
          acc[i][j] = fmaf(av[i].z, bv[j].z, acc[i][j]);
          acc[i][j] = fmaf(av[i].w, bv[j].w, acc[i][j]);
        }
    }
    __syncthreads();
  }
  float* p = part + (size_t)s * (M_NODES * NH);
  #pragma unroll
  for (int i = 0; i < 4; ++i) {
    int gr = row0 + ty + 32 * i;
    if (gr < M_NODES) {
      #pragma unroll
      for (int j = 0; j < 5; ++j)
        p[gr * NH + tx + 10 * j] = acc[i][j];
    }
  }
}

// ---------------- epilogue: x1 = relu(sum_s part[s] + b1) ----------------
__global__ void k_epi(const float* __restrict__ part, const float* __restrict__ b1,
                      float* __restrict__ x1) {
  int i = blockIdx.x * 256 + threadIdx.x;
  if (i >= M_NODES * NH) return;
  float v = part[i] + part[1000000 + i] + part[2000000 + i] + part[3000000 + i]
          + b1[i % NH];
  x1[i] = fmaxf(v, 0.f);
}

// ---------------- fused MLP layers 2..4: z = relu(relu(x1@W2+b2)@W3+b3)@W4+b4 ----------------
// grid 625, block 256 = 32 rows x 8 col-groups
__global__ __launch_bounds__(256) void k_mlp(const float* __restrict__ x1,
    const float* __restrict__ W2, const float* __restrict__ b2,
    const float* __restrict__ W3, const float* __restrict__ b3,
    const float* __restrict__ W4, const float* __restrict__ b4,
    float* __restrict__ z) {
  __shared__ float lX[32 * 51];
  __shared__ float lW2[50 * 52];
  __shared__ float lW3[50 * 52];
  __shared__ float lW4[50 * 8];
  const int tid = threadIdx.x;
  const int row0 = blockIdx.x * 32;
  for (int idx = tid; idx < 2500; idx += 256) {
    int k = idx / 50, n = idx % 50;
    lW2[k * 52 + n] = W2[idx];
    lW3[k * 52 + n] = W3[idx];
  }
  for (int idx = tid; idx < 300; idx += 256) {
    int k = idx / 6, n = idx % 6;
    lW4[k * 8 + n] = W4[idx];
  }
  for (int idx = tid; idx < 1600; idx += 256) {
    int r = idx / 50, k = idx % 50;
    int gr = row0 + r;
    lX[r * 51 + k] = (gr < M_NODES) ? x1[gr * 50 + k] : 0.f;
  }
  __syncthreads();
  const int r = tid >> 3, cg = tid & 7;
  float x[50];
  #pragma unroll
  for (int k = 0; k < 50; ++k) x[k] = lX[r * 51 + k];

  // hidden layers 2 and 3
  for (int layer = 0; layer < 2; ++layer) {
    const float* lW = (layer == 0) ? lW2 : lW3;
    const float* bg = (layer == 0) ? b2 : b3;
    float acc[7];
    #pragma unroll
    for (int j = 0; j < 7; ++j) {
      int n = cg + 8 * j;
      acc[j] = (n < 50) ? bg[n] : 0.f;
    }
    #pragma unroll
    for (int k = 0; k < 50; ++k) {
      float xk = x[k];
      #pragma unroll
      for (int j = 0; j < 7; ++j) {
        int n = cg + 8 * j;
        if (n < 50) acc[j] = fmaf(xk, lW[k * 52 + n], acc[j]);
      }
    }
    __syncthreads();
    #pragma unroll
    for (int j = 0; j < 7; ++j) {
      int n = cg + 8 * j;
      if (n < 50) lX[r * 51 + n] = fmaxf(acc[j], 0.f);
    }
    __syncthreads();
    #pragma unroll
    for (int k = 0; k < 50; ++k) x[k] = lX[r * 51 + k];
  }
  // output layer 4 (6 classes): col-groups 0..5 each produce one class
  if (cg < 6) {
    float accz = b4[cg];
    #pragma unroll
    for (int k = 0; k < 50; ++k) accz = fmaf(x[k], lW4[k * 8 + cg], accz);
    int gr = row0 + r;
    if (gr < M_NODES) z[gr * 6 + cg] = accz;
  }
}

// ---------------- KENN edge layer: znext += clause deltas (znext pre-init to zcur) ----------------
__global__ __launch_bounds__(256) void k_edge(const float* __restrict__ zcur,
    float* __restrict__ znext, const int* __restrict__ sx, const int* __restrict__ sy,
    const float* __restrict__ rel, const float* __restrict__ cw) {
  int e = blockIdx.x * 256 + threadIdx.x;
  if (e >= N_EDGES_C) return;
  int a = sx[e], b = sy[e];
  float v2 = -rel[e];
  const float2* za2 = (const float2*)(zcur + a * 6);
  const float2* zb2 = (const float2*)(zcur + b * 6);
  float2 a0 = za2[0], a1 = za2[1], a2 = za2[2];
  float2 b0 = zb2[0], b1v = zb2[1], b2v = zb2[2];
  float zax[6] = {a0.x, a0.y, a1.x, a1.y, a2.x, a2.y};
  float zbx[6] = {b0.x, b0.y, b1v.x, b1v.y, b2v.x, b2v.y};
  #pragma unroll
  for (int c = 0; c < 6; ++c) {
    float v0 = -zax[c];
    float v1 = zbx[c];
    float m = fmaxf(fmaxf(v0, v1), v2);
    float e0 = __expf(v0 - m);
    float e1 = __expf(v1 - m);
    float e2 = __expf(v2 - m);
    float w = cw[c] / (e0 + e1 + e2);
    atomicAdd(&znext[a * 6 + c], -e0 * w);
    atomicAdd(&znext[b * 6 + c],  e1 * w);
  }
}

// ---------------- final row softmax over 6 classes ----------------
__global__ void k_softmax(const float* __restrict__ z, float* __restrict__ out) {
  int i = blockIdx.x * 256 + threadIdx.x;
  if (i >= M_NODES) return;
  const float2* z2 = (const float2*)(z + i * 6);
  float2 p0 = z2[0], p1 = z2[1], p2 = z2[2];
  float v[6] = {p0.x, p0.y, p1.x, p1.y, p2.x, p2.y};
  float m = v[0];
  #pragma unroll
  for (int c = 1; c < 6; ++c) m = fmaxf(m, v[c]);
  float s = 0.f, ev[6];
  #pragma unroll
  for (int c = 0; c < 6; ++c) { ev[c] = __expf(v[c] - m); s += ev[c]; }
  float inv = 1.f / s;
  float2* o2 = (float2*)(out + i * 6);
  o2[0] = make_float2(ev[0] * inv, ev[1] * inv);
  o2[1] = make_float2(ev[2] * inv, ev[3] * inv);
  o2[2] = make_float2(ev[4] * inv, ev[5] * inv);
}

extern "C" void kernel_launch(void* const* d_in, const int* in_sizes, int n_in,
                              void* d_out, int out_size, void* d_ws, size_t ws_size,
                              hipStream_t stream) {
  const float* A   = (const float*)d_in[0];
  const float* rel = (const float*)d_in[1];
  const int*   sx  = (const int*)d_in[2];
  const int*   sy  = (const int*)d_in[3];
  const float* W1  = (const float*)d_in[4];
  const float* b1  = (const float*)d_in[5];
  const float* W2  = (const float*)d_in[6];
  const float* b2  = (const float*)d_in[7];
  const float* W3  = (const float*)d_in[8];
  const float* b3  = (const float*)d_in[9];
  const float* W4  = (const float*)d_in[10];
  const float* b4  = (const float*)d_in[11];
  const float* cw  = (const float*)d_in[12];

  float* part = (float*)d_ws;              // 4 x 1,000,000 floats
  float* x1   = part + 4 * 1000000;        // 1,000,000 floats
  float* zA   = x1 + 1000000;              // 120,000 floats
  float* zB   = zA + 120000;               // 120,000 floats

  k_gemm1<<<dim3(157, 4), 320, 0, stream>>>(A, W1, part);
  k_epi<<<(M_NODES * NH + 255) / 256, 256, 0, stream>>>(part, b1, x1);
  k_mlp<<<(M_NODES + 31) / 32, 256, 0, stream>>>(x1, W2, b2, W3, b3, W4, b4, zA);

  float* zc = zA;
  float* zn = zB;
  for (int l = 0; l < 3; ++l) {
    hipMemcpyAsync(zn, zc, 120000 * sizeof(float), hipMemcpyDeviceToDevice, stream);
    k_edge<<<N_EDGES_C / 256, 256, 0, stream>>>(zc, zn, sx, sy, rel, cw + 6 * l);
    float* t = zc; zc = zn; zn = t;
  }
  k_softmax<<<(M_NODES + 255) / 256, 256, 0, stream>>>(zc, (float*)d_out);
}

// Round 2
// 795.590 us; speedup vs baseline: 2.5746x; 2.5746x over previous
//
#include <hip/hip_runtime.h>

#define M_NODES 20000
#define K_FEATS 3703
#define PADK 3712          // 116*32
#define NH 50
#define NC 6
#define N_EDGES_C 640000

// ================= GEMM1: part[s] = A[:, ks:ke] @ W1[ks:ke, :] =================
// Bp: W1 padded to [3712][64], zero-filled (16B-aligned rows for float4 loads).
__global__ void k_padB(const float* __restrict__ W1, float* __restrict__ Bp) {
  int idx = blockIdx.x * 256 + threadIdx.x;
  if (idx >= PADK * 64) return;
  int k = idx >> 6, c = idx & 63;
  Bp[idx] = (k < K_FEATS && c < NH) ? W1[k * NH + c] : 0.f;
}

// grid (157, S), block 256. Tile 128 rows; thread = (rslot=tid>>3, cg=tid&7),
// R=4 rows (rslot+32i), C=8 cols (cg*8..+7, cols>=50 are zero-padded junk).
// A staged in LDS (36-pad, conflict-free). B loaded from Bp via depth-4
// pipelined float4 prefetch (L2-resident, 8 distinct addrs/wave -> coalesced).
__global__ __launch_bounds__(256) void k_gemm1(const float* __restrict__ A,
                                               const float* __restrict__ Bp,
                                               float* __restrict__ part, int KS) {
  __shared__ float lA[128 * 36];
  const int tid = threadIdx.x;
  const int row0 = blockIdx.x * 128;
  const int s = blockIdx.y;
  const int ks = s * KS;
  const int ke = (ks + KS < PADK) ? ks + KS : PADK;     // multiple of 32
  const int keA = (ke < K_FEATS) ? ke : K_FEATS;
  const int rslot = tid >> 3;
  const int cg = tid & 7;

  float4 acc[4][2];
  #pragma unroll
  for (int i = 0; i < 4; ++i) {
    acc[i][0] = make_float4(0.f, 0.f, 0.f, 0.f);
    acc[i][1] = make_float4(0.f, 0.f, 0.f, 0.f);
  }

  for (int k0 = ks; k0 < ke; k0 += 32) {
    // ---- stage A tile 128x32 (coalesced: 32 lanes walk k within a row) ----
    #pragma unroll
    for (int u = 0; u < 16; ++u) {
      int idx = tid + u * 256;            // exactly 4096
      int r = idx >> 5, kk = idx & 31;
      int gr = row0 + r, gk = k0 + kk;
      float v = (gr < M_NODES && gk < keA) ? A[(size_t)gr * K_FEATS + gk] : 0.f;
      lA[r * 36 + kk] = v;
    }
    __syncthreads();

    // ---- preload B pipeline: bv[p] holds B[k0+p][cg*8..+7] ----
    float4 bv[4][2];
    #pragma unroll
    for (int p = 0; p < 4; ++p) {
      const float4* Br = (const float4*)(Bp + (size_t)(k0 + p) * 64 + cg * 8);
      bv[p][0] = Br[0];
      bv[p][1] = Br[1];
    }

    #pragma unroll
    for (int kk4 = 0; kk4 < 8; ++kk4) {
      float4 av[4];
      #pragma unroll
      for (int i = 0; i < 4; ++i)
        av[i] = *(const float4*)&lA[(rslot + 32 * i) * 36 + kk4 * 4];
      #pragma unroll
      for (int kkin = 0; kkin < 4; ++kkin) {
        float4 b0 = bv[kkin][0], b1 = bv[kkin][1];
        if (kk4 < 7) {  // prefetch kk+4 (distance = 4 kk = ~256 VALU cy)
          const float4* Br =
              (const float4*)(Bp + (size_t)(k0 + kk4 * 4 + kkin + 4) * 64 + cg * 8);
          bv[kkin][0] = Br[0];
          bv[kkin][1] = Br[1];
        }
        #pragma unroll
        for (int i = 0; i < 4; ++i) {
          float a = ((const float*)&av[i])[kkin];
          acc[i][0].x = fmaf(a, b0.x, acc[i][0].x);
          acc[i][0].y = fmaf(a, b0.y, acc[i][0].y);
          acc[i][0].z = fmaf(a, b0.z, acc[i][0].z);
          acc[i][0].w = fmaf(a, b0.w, acc[i][0].w);
          acc[i][1].x = fmaf(a, b1.x, acc[i][1].x);
          acc[i][1].y = fmaf(a, b1.y, acc[i][1].y);
          acc[i][1].z = fmaf(a, b1.z, acc[i][1].z);
          acc[i][1].w = fmaf(a, b1.w, acc[i][1].w);
        }
      }
    }
    __syncthreads();
  }

  float* p = part + (size_t)s * 1000000;
  #pragma unroll
  for (int i = 0; i < 4; ++i) {
    int gr = row0 + rslot + 32 * i;
    if (gr < M_NODES) {
      #pragma unroll
      for (int h = 0; h < 2; ++h) {
        float4 v = acc[i][h];
        int c0 = cg * 8 + h * 4;
        if (c0 + 0 < NH) p[gr * NH + c0 + 0] = v.x;
        if (c0 + 1 < NH) p[gr * NH + c0 + 1] = v.y;
        if (c0 + 2 < NH) p[gr * NH + c0 + 2] = v.z;
        if (c0 + 3 < NH) p[gr * NH + c0 + 3] = v.w;
      }
    }
  }
}

// ================= epilogue: x1 = relu(sum_s part[s] + b1) =================
__global__ void k_epi(const float* __restrict__ part, const float* __restrict__ b1,
                      float* __restrict__ x1, int S) {
  int i = blockIdx.x * 256 + threadIdx.x;
  if (i >= M_NODES * NH) return;
  float v = b1[i % NH];
  for (int s = 0; s < S; ++s) v += part[(size_t)s * 1000000 + i];
  x1[i] = fmaxf(v, 0.f);
}

// ================= fused MLP layers 2..4 =================
__global__ __launch_bounds__(256) void k_mlp(const float* __restrict__ x1,
    const float* __restrict__ W2, const float* __restrict__ b2,
    const float* __restrict__ W3, const float* __restrict__ b3,
    const float* __restrict__ W4, const float* __restrict__ b4,
    float* __restrict__ z) {
  __shared__ float lX[32 * 51];
  __shared__ float lW2[50 * 52];
  __shared__ float lW3[50 * 52];
  __shared__ float lW4[50 * 8];
  const int tid = threadIdx.x;
  const int row0 = blockIdx.x * 32;
  for (int idx = tid; idx < 2500; idx += 256) {
    int k = idx / 50, n = idx % 50;
    lW2[k * 52 + n] = W2[idx];
    lW3[k * 52 + n] = W3[idx];
  }
  for (int idx = tid; idx < 300; idx += 256) {
    int k = idx / 6, n = idx % 6;
    lW4[k * 8 + n] = W4[idx];
  }
  for (int idx = tid; idx < 1600; idx += 256) {
    int r = idx / 50, k = idx % 50;
    int gr = row0 + r;
    lX[r * 51 + k] = (gr < M_NODES) ? x1[gr * 50 + k] : 0.f;
  }
  __syncthreads();
  const int r = tid >> 3, cg = tid & 7;
  float x[50];
  #pragma unroll
  for (int k = 0; k < 50; ++k) x[k] = lX[r * 51 + k];

  for (int layer = 0; layer < 2; ++layer) {
    const float* lW = (layer == 0) ? lW2 : lW3;
    const float* bg = (layer == 0) ? b2 : b3;
    float acc[7];
    #pragma unroll
    for (int j = 0; j < 7; ++j) {
      int n = cg + 8 * j;
      acc[j] = (n < 50) ? bg[n] : 0.f;
    }
    #pragma unroll
    for (int k = 0; k < 50; ++k) {
      float xk = x[k];
      #pragma unroll
      for (int j = 0; j < 7; ++j) {
        int n = cg + 8 * j;
        if (n < 50) acc[j] = fmaf(xk, lW[k * 52 + n], acc[j]);
      }
    }
    __syncthreads();
    #pragma unroll
    for (int j = 0; j < 7; ++j) {
      int n = cg + 8 * j;
      if (n < 50) lX[r * 51 + n] = fmaxf(acc[j], 0.f);
    }
    __syncthreads();
    #pragma unroll
    for (int k = 0; k < 50; ++k) x[k] = lX[r * 51 + k];
  }
  if (cg < 6) {
    float accz = b4[cg];
    #pragma unroll
    for (int k = 0; k < 50; ++k) accz = fmaf(x[k], lW4[k * 8 + cg], accz);
    int gr = row0 + r;
    if (gr < M_NODES) z[gr * 6 + cg] = accz;
  }
}

// ================= CSR incidence build =================
__global__ void k_count(const int* __restrict__ sx, const int* __restrict__ sy,
                        int* __restrict__ cnt) {
  int e = blockIdx.x * 256 + threadIdx.x;
  if (e >= N_EDGES_C) return;
  atomicAdd(&cnt[sx[e]], 1);
  atomicAdd(&cnt[sy[e]], 1);
}

__global__ __launch_bounds__(1024) void k_scan(const int* __restrict__ cnt,
                                               int* __restrict__ off,
                                               int* __restrict__ cur) {
  __shared__ int sums[1024];
  int t = threadIdx.x;
  int base = t * 20;
  int local[20];
  int s = 0;
  #pragma unroll
  for (int j = 0; j < 20; ++j) {
    int idx = base + j;
    int v = (idx < M_NODES) ? cnt[idx] : 0;
    local[j] = s;
    s += v;
  }
  sums[t] = s;
  __syncthreads();
  for (int d = 1; d < 1024; d <<= 1) {
    int v = (t >= d) ? sums[t - d] : 0;
    __syncthreads();
    sums[t] += v;
    __syncthreads();
  }
  int excl = sums[t] - s;
  #pragma unroll
  for (int j = 0; j < 20; ++j) {
    int idx = base + j;
    if (idx < M_NODES) {
      int o = excl + local[j];
      off[idx] = o;
      cur[idx] = o;
    }
  }
  if (t == 1023) off[M_NODES] = sums[1023];
}

__global__ void k_scatter(const int* __restrict__ sx, const int* __restrict__ sy,
                          int* __restrict__ cur, int* __restrict__ entries) {
  int e = blockIdx.x * 256 + threadIdx.x;
  if (e >= N_EDGES_C) return;
  int p = atomicAdd(&cur[sx[e]], 1);
  entries[p] = (e << 1);
  int q = atomicAdd(&cur[sy[e]], 1);
  entries[q] = (e << 1) | 1;
}

// ================= KENN gather layer (atomic-free) =================
// thread = (node n, class c, quarter s of n's incidence list) -> partial[s][n*6+c]
__global__ __launch_bounds__(256) void k_gather(const float* __restrict__ z,
    const int* __restrict__ off, const int* __restrict__ entries,
    const int* __restrict__ sx, const int* __restrict__ sy,
    const float* __restrict__ rel, const float* __restrict__ cw,
    float* __restrict__ partial) {
  int t = blockIdx.x * 256 + threadIdx.x;
  if (t >= M_NODES * NC * 4) return;
  int s = t & 3;
  int rest = t >> 2;
  int c = rest % NC;
  int n = rest / NC;
  int o0 = off[n];
  int deg = off[n + 1] - o0;
  int lo = o0 + ((deg * s) >> 2);
  int hi = o0 + ((deg * (s + 1)) >> 2);
  float zn = z[n * 6 + c];
  float w = cw[c];
  float dz = 0.f;

  #define PROC(I) {                                        \
    int ent = entries[I];                                  \
    int e = ent >> 1;                                      \
    int side = ent & 1;                                    \
    int partner = side ? sx[e] : sy[e];                    \
    float r = rel[e];                                      \
    float zp = z[partner * 6 + c];                         \
    float zx = side ? zp : zn;                             \
    float zy = side ? zn : zp;                             \
    float v0 = -zx, v1 = zy, v2 = -r;                      \
    float m = fmaxf(fmaxf(v0, v1), v2);                    \
    float e0 = __expf(v0 - m);                             \
    float e1 = __expf(v1 - m);                             \
    float e2 = __expf(v2 - m);                             \
    float inv = w / (e0 + e1 + e2);                        \
    dz += (side ? e1 : -e0) * inv;                         \
  }

  int i = lo;
  for (; i + 1 < hi; i += 2) { PROC(i); PROC(i + 1); }
  if (i < hi) PROC(i);
  #undef PROC

  partial[s * (M_NODES * NC) + n * 6 + c] = dz;
}

__global__ void k_combine(const float* __restrict__ zc, const float* __restrict__ partial,
                          float* __restrict__ zn) {
  int i = blockIdx.x * 256 + threadIdx.x;
  if (i >= M_NODES * NC) return;
  zn[i] = zc[i] + partial[i] + partial[120000 + i] + partial[240000 + i]
        + partial[360000 + i];
}

// ================= final row softmax =================
__global__ void k_softmax(const float* __restrict__ z, float* __restrict__ out) {
  int i = blockIdx.x * 256 + threadIdx.x;
  if (i >= M_NODES) return;
  const float2* z2 = (const float2*)(z + i * 6);
  float2 p0 = z2[0], p1 = z2[1], p2 = z2[2];
  float v[6] = {p0.x, p0.y, p1.x, p1.y, p2.x, p2.y};
  float m = v[0];
  #pragma unroll
  for (int c = 1; c < 6; ++c) m = fmaxf(m, v[c]);
  float sum = 0.f, ev[6];
  #pragma unroll
  for (int c = 0; c < 6; ++c) { ev[c] = __expf(v[c] - m); sum += ev[c]; }
  float inv = 1.f / sum;
  float2* o2 = (float2*)(out + i * 6);
  o2[0] = make_float2(ev[0] * inv, ev[1] * inv);
  o2[1] = make_float2(ev[2] * inv, ev[3] * inv);
  o2[2] = make_float2(ev[4] * inv, ev[5] * inv);
}

extern "C" void kernel_launch(void* const* d_in, const int* in_sizes, int n_in,
                              void* d_out, int out_size, void* d_ws, size_t ws_size,
                              hipStream_t stream) {
  const float* A   = (const float*)d_in[0];
  const float* rel = (const float*)d_in[1];
  const int*   sx  = (const int*)d_in[2];
  const int*   sy  = (const int*)d_in[3];
  const float* W1  = (const float*)d_in[4];
  const float* b1  = (const float*)d_in[5];
  const float* W2  = (const float*)d_in[6];
  const float* b2  = (const float*)d_in[7];
  const float* W3  = (const float*)d_in[8];
  const float* b3  = (const float*)d_in[9];
  const float* W4  = (const float*)d_in[10];
  const float* b4  = (const float*)d_in[11];
  const float* cw  = (const float*)d_in[12];

  // split-K factor: 8 if workspace allows, else 4 (21.9 MB, proven safe)
  const int S  = (ws_size >= (size_t)40 * 1024 * 1024) ? 8 : 4;
  const int KS = (S == 8) ? 480 : 928;   // multiples of 32; S*KS >= 3712

  float* base = (float*)d_ws;
  float* part = base;                       // S * 1e6 floats (dead after k_epi)
  float* x1   = base + (size_t)S * 1000000; // 1e6 floats (dead after k_mlp)
  float* zA   = x1 + 1000000;               // 120000
  float* zB   = zA + 120000;                // 120000
  float* Bp   = zB + 120000;                // 237568 (live through k_gemm1)

  // CSR arrays alias the (dead) part region
  int*   cnt     = (int*)base;              // 20001
  int*   off     = (int*)base + 24576;      // 20001
  int*   cur     = (int*)base + 49152;      // 20001
  int*   entries = (int*)base + 73728;      // 1,280,000
  float* partial = base + 1376256;          // 480,000

  k_padB<<<(PADK * 64 + 255) / 256, 256, 0, stream>>>(W1, Bp);
  k_gemm1<<<dim3(157, S), 256, 0, stream>>>(A, Bp, part, KS);
  k_epi<<<(M_NODES * NH + 255) / 256, 256, 0, stream>>>(part, b1, x1, S);
  k_mlp<<<(M_NODES + 31) / 32, 256, 0, stream>>>(x1, W2, b2, W3, b3, W4, b4, zA);

  hipMemsetAsync(cnt, 0, (M_NODES + 1) * sizeof(int), stream);
  k_count<<<(N_EDGES_C + 255) / 256, 256, 0, stream>>>(sx, sy, cnt);
  k_scan<<<1, 1024, 0, stream>>>(cnt, off, cur);
  k_scatter<<<(N_EDGES_C + 255) / 256, 256, 0, stream>>>(sx, sy, cur, entries);

  float* zc = zA;
  float* zn = zB;
  for (int l = 0; l < 3; ++l) {
    k_gather<<<(M_NODES * NC * 4 + 255) / 256, 256, 0, stream>>>(
        zc, off, entries, sx, sy, rel, cw + 6 * l, partial);
    k_combine<<<(M_NODES * NC + 255) / 256, 256, 0, stream>>>(zc, partial, zn);
    float* t = zc; zc = zn; zn = t;
  }
  k_softmax<<<(M_NODES + 255) / 256, 256, 0, stream>>>(zc, (float*)d_out);
}